// Round 11
// baseline (10718.022 us; speedup 1.0000x reference)
//
#include <hip/hip_runtime.h>
#include <hip/hip_fp16.h>

#define T_STEPS 512
#define NB      64
#define NI      128
#define NH      256
#define LK      16
#define RS      32
#define NS      (LK + RS)

// ws layout (bytes)
#define WP_OFF   0            // uint4[192*256]: gate weights, k-pairs packed as 4 half2 (f,i,o,g)
#define VAP8_OFF 786432       // uint4[32*256]: Va^T, 8 consecutive k per entry, per output h
#define UAP8_OFF 917504       // uint4[32*256]: Ua^T, same layout
#define GX_OFF   5242880      // fp16 uint2[512*64*256]: precomputed x-part of gates (f,i,o,g)
#define WS_NEED  (GX_OFF + (size_t)T_STEPS * NB * NH * 8)

typedef _Float16 half2v __attribute__((ext_vector_type(2)));
typedef unsigned int u32x4 __attribute__((ext_vector_type(4)));
typedef unsigned int u32x2 __attribute__((ext_vector_type(2)));

// non-temporal 16B/8B loads: nt flag -> no L1 allocation for streaming weights
__device__ __forceinline__ u32x4 ntl4(const void* p) {
    return __builtin_nontemporal_load((const u32x4*)p);
}
__device__ __forceinline__ u32x2 ntl2(const void* p) {
    return __builtin_nontemporal_load((const u32x2*)p);
}
__device__ __forceinline__ float2 h2f2(unsigned int u) {
    __half2 h = *(__half2*)&u;
    return __half22float2(h);
}

// v_dot2_f32_f16: 2 half MACs + f32 accumulate in ONE VALU op
__device__ __forceinline__ float hdot(unsigned int w, unsigned int s, float c) {
    return __builtin_amdgcn_fdot2(__builtin_bit_cast(half2v, w),
                                  __builtin_bit_cast(half2v, s), c, false);
}

__device__ __forceinline__ float fsig(float x) {
    return __builtin_amdgcn_rcpf(1.0f + __expf(-x));
}
__device__ __forceinline__ float ftanh(float x) {
    x = fminf(15.0f, fmaxf(-15.0f, x));
    float e = __expf(2.0f * x);
    return (e - 1.0f) * __builtin_amdgcn_rcpf(e + 1.0f);
}

__global__ void prep_weights(const float* __restrict__ Wf, const float* __restrict__ Wi,
                             const float* __restrict__ Wo, const float* __restrict__ Wg,
                             const float* __restrict__ Ua, const float* __restrict__ Va,
                             unsigned char* __restrict__ ws) {
    int e = blockIdx.x * 256 + threadIdx.x;   // 0..65535
    if (e < 49152) {                          // WP: e = k2*256 + h
        int h = e & 255, k2 = e >> 8, k = 2 * k2;
        uint4 w; __half2 t;
        t = __floats2half2_rn(Wf[h * 384 + k], Wf[h * 384 + k + 1]); w.x = *(unsigned int*)&t;
        t = __floats2half2_rn(Wi[h * 384 + k], Wi[h * 384 + k + 1]); w.y = *(unsigned int*)&t;
        t = __floats2half2_rn(Wo[h * 384 + k], Wo[h * 384 + k + 1]); w.z = *(unsigned int*)&t;
        t = __floats2half2_rn(Wg[h * 384 + k], Wg[h * 384 + k + 1]); w.w = *(unsigned int*)&t;
        ((uint4*)(ws + WP_OFF))[e] = w;
    } else {                                  // Va/Ua 8-k packs
        int e2 = e - 49152;                   // 0..16383
        const float* S = (e2 < 8192) ? Va : Ua;
        int e3 = e2 & 8191;
        int h = e3 & 255, j = e3 >> 8, k = 8 * j;
        uint4 w; __half2 t;
        t = __floats2half2_rn(S[h * 256 + k + 0], S[h * 256 + k + 1]); w.x = *(unsigned int*)&t;
        t = __floats2half2_rn(S[h * 256 + k + 2], S[h * 256 + k + 3]); w.y = *(unsigned int*)&t;
        t = __floats2half2_rn(S[h * 256 + k + 4], S[h * 256 + k + 5]); w.z = *(unsigned int*)&t;
        t = __floats2half2_rn(S[h * 256 + k + 6], S[h * 256 + k + 7]); w.w = *(unsigned int*)&t;
        ((uint4*)(ws + VAP8_OFF))[e2] = w;    // VaP8 then UaP8 contiguous
    }
}

// Parallel GEMM: gate_x[t][b][h][4g] = W_x @ x_t
__global__ __launch_bounds__(256) void gx_gemm(const float* __restrict__ x,
                                               unsigned char* __restrict__ ws) {
    const int t = blockIdx.x, bg = blockIdx.y, tid = threadIdx.x;
    const uint4* __restrict__ WP = (const uint4*)(ws + WP_OFF);
    uint2* __restrict__ GX = (uint2*)(ws + GX_OFF);
    __shared__ float s_xx[16 * 128];
    const float* xb = x + ((size_t)t * NB + bg * 16) * NI;
#pragma unroll
    for (int r = 0; r < 8; ++r) s_xx[tid + 256 * r] = xb[tid + 256 * r];
    __syncthreads();
    const int h = tid;
    float acc[16][4];
#pragma unroll
    for (int bb = 0; bb < 16; ++bb) { acc[bb][0] = acc[bb][1] = acc[bb][2] = acc[bb][3] = 0.f; }
    for (int k2 = 128; k2 < 192; ++k2) {
        uint4 w = WP[k2 * NH + h];
        float2 wf = __half22float2(*(const __half2*)&w.x);
        float2 wi = __half22float2(*(const __half2*)&w.y);
        float2 wo = __half22float2(*(const __half2*)&w.z);
        float2 wg = __half22float2(*(const __half2*)&w.w);
        int kk = 2 * k2 - 256;
#pragma unroll
        for (int bb = 0; bb < 16; ++bb) {
            float2 xv = *(const float2*)(s_xx + bb * 128 + kk);
            acc[bb][0] += wf.x * xv.x + wf.y * xv.y;
            acc[bb][1] += wi.x * xv.x + wi.y * xv.y;
            acc[bb][2] += wo.x * xv.x + wo.y * xv.y;
            acc[bb][3] += wg.x * xv.x + wg.y * xv.y;
        }
    }
#pragma unroll
    for (int bb = 0; bb < 16; ++bb) {
        __half2 p0 = __floats2half2_rn(acc[bb][0], acc[bb][1]);
        __half2 p1 = __floats2half2_rn(acc[bb][2], acc[bb][3]);
        uint2 u; u.x = *(unsigned int*)&p0; u.y = *(unsigned int*)&p1;
        GX[((size_t)t * NB + bg * 16 + bb) * NH + h] = u;
    }
}

// One block (1024 threads, 16 waves) per batch sample. R2-proven structure
// (5 barriers/step, lraw/lua in LDS) with ALL weight-stream loads (VaP8/UaP8 in P1,
// WP in P5, GX) marked non-temporal: the 768KB/step weight set never re-hits L1,
// so nt removes the L1 allocation/fill-port serialization on the streaming path.
template <int USE_GX>
__global__ __launch_bounds__(1024, 1) void rel_lstm(
    const float* __restrict__ x,
    const float* __restrict__ bf_g, const float* __restrict__ bi_g,
    const float* __restrict__ bo_g, const float* __restrict__ bg_g,
    const float* __restrict__ vv_g,
    unsigned char* __restrict__ ws, float* __restrict__ out) {
    const int tid = threadIdx.x;
    const int b   = blockIdx.x;
    const int wv  = tid >> 6;
    const int ln  = tid & 63;
    const int h16 = (wv << 4) | (ln & 15);   // owner h
    const int kc  = ln >> 4;                 // in-wave k-chunk 0..3

    const uint4* __restrict__ WP   = (const uint4*)(ws + WP_OFF);
    const uint4* __restrict__ VaP8 = (const uint4*)(ws + VAP8_OFF);
    const uint4* __restrict__ UaP8 = (const uint4*)(ws + UAP8_OFF);
    const uint2* __restrict__ GX   = (const uint2*)(ws + GX_OFF);

    __shared__ __align__(16) _Float16 s_in_h[NH + NI];   // half st | half x (non-GX)
    __shared__ __align__(16) _Float16 s_hid_h[NH];       // half h_{t-1}
    __shared__ __align__(16) float s_q[NH];              // Va @ st (combined)
    __shared__ __align__(16) float s_v[NH];
    __shared__ __align__(16) float s_mem[LK][NH];        // hidden ring (float)
    __shared__ __align__(16) float s_memua[LK][NH + 8];  // Ua@h ring (+8 pad)
    __shared__ __align__(16) float s_lraw[RS * NH];      // long-mem raw hiddens
    __shared__ __align__(16) float s_lua[RS * NH];       // long-mem Ua@h
    __shared__ float s_es[NS], s_al[NS];
    __shared__ float s_scores[T_STEPS];
    __shared__ float s_mask[RS], s_buck[RS];
    __shared__ float s_minv;
    __shared__ int s_minp, s_fill, s_upd, s_pos;

    // ---- init ----
    for (int i = tid; i < LK * NH; i += 1024) ((float*)s_mem)[i] = 0.f;
    for (int i = tid; i < LK * (NH + 8); i += 1024) ((float*)s_memua)[i] = 0.f;
    for (int i = tid; i < RS * NH; i += 1024) { s_lraw[i] = 0.f; s_lua[i] = 0.f; }
    if (tid < T_STEPS) s_scores[tid] = 0.f;
    if (tid < NH) s_v[tid] = vv_g[tid];
    if (tid < (NH + NI) / 2) ((unsigned int*)s_in_h)[tid] = 0u;
    if (tid < RS) { s_mask[tid] = -1e30f; s_buck[tid] = 0.f; }
    if (tid == 0) { s_fill = 0; s_upd = 0; s_pos = 0; s_minv = 0.f; s_minp = 0; }
    float bfv = 0.f, biv = 0.f, bov = 0.f, bgv = 0.f;
    if (kc == 0) { bfv = bf_g[h16]; biv = bi_g[h16]; bov = bo_g[h16]; bgv = bg_g[h16]; }
    if (!USE_GX && tid < 64) {            // x_0 half-pack
        float2 xv = ((const float2*)(x + (size_t)b * NI))[tid];
        __half2 hx = __floats2half2_rn(xv.x, xv.y);
        ((unsigned int*)s_in_h)[NH / 2 + tid] = *(unsigned int*)&hx;
    }
    float ct = 0.f;
    int base = 0;
    __syncthreads();

    for (int t = 0; t < T_STEPS; ++t) {
        float evA = 0.f, evB = 0.f;
        u32x2 gx = {0u, 0u};
        if (USE_GX && kc == 0) gx = ntl2(&GX[((size_t)t * NB + b) * NH + h16]);
        if (t > 0) {
            // ---- P1: Va@st (waves 0-7) / Ua@h_{t-1} (waves 8-15), nt loads, fdot2 ----
            {
                const uint4* P   = (wv < 8) ? VaP8 : UaP8;
                const uint4* SRC = (wv < 8) ? (const uint4*)s_in_h : (const uint4*)s_hid_h;
                const int hh = ((wv & 7) << 5) | (ln & 31);   // output h (32 per wave)
                const int ch = ln >> 5;                       // k half 0/1
                float acc = 0.f;
#pragma unroll 8
                for (int jj = 0; jj < 16; ++jj) {
                    int j = (ch << 4) | jj;
                    u32x4 w = ntl4(&P[(j << 8) + hh]);
                    uint4 s = SRC[j];                          // LDS broadcast b128
                    acc = hdot(w.x, s.x, acc);
                    acc = hdot(w.y, s.y, acc);
                    acc = hdot(w.z, s.z, acc);
                    acc = hdot(w.w, s.w, acc);
                }
                acc += __shfl_xor(acc, 32, 64);
                if (ch == 0) {
                    if (wv < 8) s_q[hh] = acc;
                    else        s_memua[(base + LK - 1) & (LK - 1)][hh] = acc; // persist newest
                }
                if (kc == 1) {               // prefetch evictee (slot stable since t-15)
                    int p0 = base & (LK - 1);
                    evA = s_mem[p0][h16];
                    evB = s_memua[p0][h16];
                }
                if (!USE_GX && tid < 64) {                     // x_t half-pack
                    float2 xv = ((const float2*)(x + ((size_t)t * NB + b) * NI))[tid];
                    __half2 hx = __floats2half2_rn(xv.x, xv.y);
                    ((unsigned int*)s_in_h)[NH / 2 + tid] = *(unsigned int*)&hx;
                }
            }
            __syncthreads();
            // ---- P2: attention scores (48 rows x 16 lanes, float4 loads) + argmin ----
            if (tid < 768) {
                const int row = tid >> 4, l = tid & 15;
                bool skip;
                const float* ua;
                if (row < LK) { skip = row < LK - t; ua = s_memua[(base + row) & (LK - 1)]; }
                else          { skip = s_mask[row - LK] < -1e29f; ua = s_lua + (row - LK) * NH; }
                float esv = -1e30f;
                if (!skip) {
                    float p = 0.f;
#pragma unroll
                    for (int jj = 0; jj < 4; ++jj) {
                        int hh = (l << 2) + (jj << 6);   // 2-way bank aliasing only
                        float4 q4 = *(const float4*)(s_q + hh);
                        float4 v4 = *(const float4*)(s_v + hh);
                        float4 u4 = *(const float4*)(ua + hh);
                        p += v4.x * ftanh(q4.x + u4.x);
                        p += v4.y * ftanh(q4.y + u4.y);
                        p += v4.z * ftanh(q4.z + u4.z);
                        p += v4.w * ftanh(q4.w + u4.w);
                    }
                    p += __shfl_xor(p, 1, 16);
                    p += __shfl_xor(p, 2, 16);
                    p += __shfl_xor(p, 4, 16);
                    p += __shfl_xor(p, 8, 16);
                    esv = p;
                }
                if (l == 0) s_es[row] = esv;
            } else if (tid >= 960 && tid < 992) {   // first-min argmin over s_buck
                int l = tid - 960;
                float v = s_buck[l]; int idx = l;
#pragma unroll
                for (int off = 1; off < 32; off <<= 1) {
                    float v2 = __shfl_xor(v, off, 32);
                    int  i2 = __shfl_xor(idx, off, 32);
                    if (v2 < v || (v2 == v && i2 < idx)) { v = v2; idx = i2; }
                }
                if (l == 0) { s_minv = v; s_minp = idx; }
            }
            __syncthreads();
            // ---- P3: softmax + detached score accum + bucket decision (wave 0) ----
            if (tid < 64) {
                float e = (tid < NS) ? s_es[tid] : -1e30f;
                float m = e;
#pragma unroll
                for (int off = 32; off; off >>= 1) m = fmaxf(m, __shfl_xor(m, off, 64));
                float a = (tid < NS) ? __expf(e - m) : 0.f;
                float ssum = a;
#pragma unroll
                for (int off = 32; off; off >>= 1) ssum += __shfl_xor(ssum, off, 64);
                float al = a * __builtin_amdgcn_rcpf(ssum);
                if (tid < NS) s_al[tid] = al;
                float cs = 0.f;
                if (tid < LK) {
                    int time = t - LK + tid;
                    if (time >= 0) {
                        float ns = s_scores[time] + al;
                        s_scores[time] = ns;
                        cs = ns;                      // lane 0: candidate score, in-register
                    }
                }
                if (tid == 0) {
                    int upd = 0, pos = 0;
                    if (t >= LK) {
                        int fill = s_fill;
                        bool full = fill >= RS;
                        upd = (!full) || (cs > s_minv);
                        pos = full ? s_minp : fill;
                        if (upd) { s_mask[pos] = 0.f; s_buck[pos] = cs; if (!full) s_fill = fill + 1; }
                    }
                    s_upd = upd; s_pos = pos;
                }
            }
            __syncthreads();
            // ---- P4: ct_att (12 slots per kc, in-wave combine) + st ----
            {
                float catt = 0.f;
                const int n0 = kc * 12;
#pragma unroll
                for (int n = n0; n < n0 + 12; ++n) {
                    float a = s_al[n];
                    if (n < LK) catt += a * s_mem[(base + n) & (LK - 1)][h16];
                    else if (a != 0.f) catt += a * s_lraw[(n - LK) * NH + h16];
                }
                catt += __shfl_xor(catt, 16, 64);
                catt += __shfl_xor(catt, 32, 64);
                if (kc == 0) {
                    float stv = 0.5f * (s_mem[(base + LK - 1) & (LK - 1)][h16] + catt);
                    s_in_h[h16] = (_Float16)stv;     // half shadow (only consumer is fdot2)
                }
            }
            __syncthreads();
        }
        // ---- P5: gates via fdot2 (in-wave 4-way k-split), nt weight loads ----
        {
            constexpr int KP = USE_GX ? 32 : 48;
            const unsigned int* S2 = (const unsigned int*)s_in_h;
            float af = 0.f, ai = 0.f, ao = 0.f, ag = 0.f;
            const int lo = kc * KP;
#pragma unroll 8
            for (int k2 = lo; k2 < lo + KP; ++k2) {
                u32x4 w = ntl4(&WP[(k2 << 8) + h16]);
                unsigned int s2 = S2[k2];            // LDS broadcast b32
                af = hdot(w.x, s2, af);
                ai = hdot(w.y, s2, ai);
                ao = hdot(w.z, s2, ao);
                ag = hdot(w.w, s2, ag);
            }
            af += __shfl_xor(af, 16, 64); af += __shfl_xor(af, 32, 64);
            ai += __shfl_xor(ai, 16, 64); ai += __shfl_xor(ai, 32, 64);
            ao += __shfl_xor(ao, 16, 64); ao += __shfl_xor(ao, 32, 64);
            ag += __shfl_xor(ag, 16, 64); ag += __shfl_xor(ag, 32, 64);
            if (kc == 0) {
                float pf = af + bfv, pi = ai + biv, po = ao + bov, pg = ag + bgv;
                if (USE_GX) {
                    float2 fi = h2f2(gx.x);
                    float2 og = h2f2(gx.y);
                    pf += fi.x; pi += fi.y; po += og.x; pg += og.y;
                }
                float f  = fsig(pf);
                float ii = fsig(pi);
                float o  = fsig(po);
                float g  = ftanh(pg);
                ct = f * ct + ii * g;                // t=0: ct=0 -> matches reference
                float hid = o * ftanh(ct);
                out[((size_t)t * NB + b) * NH + h16] = hid;
                s_mem[base & (LK - 1)][h16] = hid;
                s_hid_h[h16] = (_Float16)hid;
            } else if (kc == 1 && s_upd) {           // eviction writes (after P4 lraw reads)
                s_lraw[s_pos * NH + h16] = evA;
                s_lua[s_pos * NH + h16]  = evB;
            }
        }
        base++;
        __syncthreads();
    }
}

extern "C" void kernel_launch(void* const* d_in, const int* in_sizes, int n_in,
                              void* d_out, int out_size, void* d_ws, size_t ws_size,
                              hipStream_t stream) {
    const float* x  = (const float*)d_in[0];
    const float* Wf = (const float*)d_in[1];
    const float* bf = (const float*)d_in[2];
    const float* Wi = (const float*)d_in[3];
    const float* bi = (const float*)d_in[4];
    const float* Wo = (const float*)d_in[5];
    const float* bo = (const float*)d_in[6];
    const float* Wg = (const float*)d_in[7];
    const float* bg = (const float*)d_in[8];
    const float* Ua = (const float*)d_in[9];
    const float* Va = (const float*)d_in[10];
    const float* vv = (const float*)d_in[11];
    unsigned char* ws = (unsigned char*)d_ws;
    float* out = (float*)d_out;

    prep_weights<<<256, 256, 0, stream>>>(Wf, Wi, Wo, Wg, Ua, Va, ws);
    if (ws_size >= WS_NEED) {
        gx_gemm<<<dim3(T_STEPS, 4), 256, 0, stream>>>(x, ws);
        rel_lstm<1><<<NB, 1024, 0, stream>>>(x, bf, bi, bo, bg, vv, ws, out);
    } else {
        rel_lstm<0><<<NB, 1024, 0, stream>>>(x, bf, bi, bo, bg, vv, ws, out);
    }
}

// Round 12
// 5056.805 us; speedup vs baseline: 2.1195x; 2.1195x over previous
//
#include <hip/hip_runtime.h>
#include <hip/hip_fp16.h>

#define T_STEPS 512
#define NB      64
#define NI      128
#define NH      256
#define LK      16
#define RS      32
#define NS      (LK + RS)

// ws layout (bytes)
#define WP_OFF   0            // uint4[192*256]: gate weights, k-pairs packed as 4 half2 (f,i,o,g)
#define VAP8_OFF 786432       // uint4[32*256]: Va^T, 8 consecutive k per entry, per output h
#define UAP8_OFF 917504       // uint4[32*256]: Ua^T, same layout (contiguous after VaP8)
#define GX_OFF   5242880      // fp16 uint2[512*64*256]: precomputed x-part of gates (f,i,o,g)
#define WS_NEED  (GX_OFF + (size_t)T_STEPS * NB * NH * 8)

typedef _Float16 half2v __attribute__((ext_vector_type(2)));

// ---- sc0 (L1-bypass, L2-allocate) streaming loads via buffer intrinsics ----
// cpol bit0 = SC0 on gfx940+/gfx950: load bypasses L1, still hits/allocates L2.
// (R11 showed nt evicts L2 too -> 734MB HBM refetch. sc0 keeps L2 residency.)
#if defined(__has_builtin)
# if __has_builtin(__builtin_amdgcn_make_buffer_rsrc) && \
     __has_builtin(__builtin_amdgcn_raw_buffer_load_b128) && \
     __has_builtin(__builtin_amdgcn_raw_buffer_load_b64)
#  define USE_BUFLD 1
# endif
#endif
#ifndef USE_BUFLD
# define USE_BUFLD 0
#endif

template <typename D, typename S>
__device__ __forceinline__ D bcastv(S s) {
    static_assert(sizeof(D) == sizeof(S), "size mismatch");
    D d; __builtin_memcpy(&d, &s, sizeof(D)); return d;
}

#if USE_BUFLD
#define DECL_RSRC(name, ptr) \
    auto name = __builtin_amdgcn_make_buffer_rsrc((void*)(ptr), (short)0, -1, 0x00020000)
#define LD16(name, ptr, idx) \
    bcastv<uint4>(__builtin_amdgcn_raw_buffer_load_b128(name, (int)((idx) * 16), 0, 1))
#define LD8(name, ptr, idx) \
    bcastv<uint2>(__builtin_amdgcn_raw_buffer_load_b64(name, (int)((idx) * 8), 0, 1))
#else
#define DECL_RSRC(name, ptr) int name = 0; (void)name
#define LD16(name, ptr, idx) ((ptr)[idx])
#define LD8(name, ptr, idx)  ((ptr)[idx])
#endif

// v_dot2_f32_f16: 2 half MACs + f32 accumulate in ONE VALU op
__device__ __forceinline__ float hdot(unsigned int w, unsigned int s, float c) {
    return __builtin_amdgcn_fdot2(__builtin_bit_cast(half2v, w),
                                  __builtin_bit_cast(half2v, s), c, false);
}

__device__ __forceinline__ float fsig(float x) {
    return __builtin_amdgcn_rcpf(1.0f + __expf(-x));
}
__device__ __forceinline__ float ftanh(float x) {
    x = fminf(15.0f, fmaxf(-15.0f, x));
    float e = __expf(2.0f * x);
    return (e - 1.0f) * __builtin_amdgcn_rcpf(e + 1.0f);
}

__global__ void prep_weights(const float* __restrict__ Wf, const float* __restrict__ Wi,
                             const float* __restrict__ Wo, const float* __restrict__ Wg,
                             const float* __restrict__ Ua, const float* __restrict__ Va,
                             unsigned char* __restrict__ ws) {
    int e = blockIdx.x * 256 + threadIdx.x;   // 0..65535
    if (e < 49152) {                          // WP: e = k2*256 + h
        int h = e & 255, k2 = e >> 8, k = 2 * k2;
        uint4 w; __half2 t;
        t = __floats2half2_rn(Wf[h * 384 + k], Wf[h * 384 + k + 1]); w.x = *(unsigned int*)&t;
        t = __floats2half2_rn(Wi[h * 384 + k], Wi[h * 384 + k + 1]); w.y = *(unsigned int*)&t;
        t = __floats2half2_rn(Wo[h * 384 + k], Wo[h * 384 + k + 1]); w.z = *(unsigned int*)&t;
        t = __floats2half2_rn(Wg[h * 384 + k], Wg[h * 384 + k + 1]); w.w = *(unsigned int*)&t;
        ((uint4*)(ws + WP_OFF))[e] = w;
    } else {                                  // Va/Ua 8-k packs
        int e2 = e - 49152;                   // 0..16383
        const float* S = (e2 < 8192) ? Va : Ua;
        int e3 = e2 & 8191;
        int h = e3 & 255, j = e3 >> 8, k = 8 * j;
        uint4 w; __half2 t;
        t = __floats2half2_rn(S[h * 256 + k + 0], S[h * 256 + k + 1]); w.x = *(unsigned int*)&t;
        t = __floats2half2_rn(S[h * 256 + k + 2], S[h * 256 + k + 3]); w.y = *(unsigned int*)&t;
        t = __floats2half2_rn(S[h * 256 + k + 4], S[h * 256 + k + 5]); w.z = *(unsigned int*)&t;
        t = __floats2half2_rn(S[h * 256 + k + 6], S[h * 256 + k + 7]); w.w = *(unsigned int*)&t;
        ((uint4*)(ws + VAP8_OFF))[e2] = w;    // VaP8 then UaP8 contiguous
    }
}

// Parallel GEMM: gate_x[t][b][h][4g] = W_x @ x_t
__global__ __launch_bounds__(256) void gx_gemm(const float* __restrict__ x,
                                               unsigned char* __restrict__ ws) {
    const int t = blockIdx.x, bg = blockIdx.y, tid = threadIdx.x;
    const uint4* __restrict__ WP = (const uint4*)(ws + WP_OFF);
    uint2* __restrict__ GX = (uint2*)(ws + GX_OFF);
    __shared__ float s_xx[16 * 128];
    const float* xb = x + ((size_t)t * NB + bg * 16) * NI;
#pragma unroll
    for (int r = 0; r < 8; ++r) s_xx[tid + 256 * r] = xb[tid + 256 * r];
    __syncthreads();
    const int h = tid;
    float acc[16][4];
#pragma unroll
    for (int bb = 0; bb < 16; ++bb) { acc[bb][0] = acc[bb][1] = acc[bb][2] = acc[bb][3] = 0.f; }
    for (int k2 = 128; k2 < 192; ++k2) {
        uint4 w = WP[k2 * NH + h];
        float2 wf = __half22float2(*(const __half2*)&w.x);
        float2 wi = __half22float2(*(const __half2*)&w.y);
        float2 wo = __half22float2(*(const __half2*)&w.z);
        float2 wg = __half22float2(*(const __half2*)&w.w);
        int kk = 2 * k2 - 256;
#pragma unroll
        for (int bb = 0; bb < 16; ++bb) {
            float2 xv = *(const float2*)(s_xx + bb * 128 + kk);
            acc[bb][0] += wf.x * xv.x + wf.y * xv.y;
            acc[bb][1] += wi.x * xv.x + wi.y * xv.y;
            acc[bb][2] += wo.x * xv.x + wo.y * xv.y;
            acc[bb][3] += wg.x * xv.x + wg.y * xv.y;
        }
    }
#pragma unroll
    for (int bb = 0; bb < 16; ++bb) {
        __half2 p0 = __floats2half2_rn(acc[bb][0], acc[bb][1]);
        __half2 p1 = __floats2half2_rn(acc[bb][2], acc[bb][3]);
        uint2 u; u.x = *(unsigned int*)&p0; u.y = *(unsigned int*)&p1;
        GX[((size_t)t * NB + bg * 16 + bb) * NH + h] = u;
    }
}

// One block (1024 threads, 16 waves) per batch sample. R2-proven structure
// (5 barriers/step, lraw/lua in LDS). Weight-stream loads (VaP8/UaP8 in P1, WP in P5,
// GX) use sc0 buffer loads: bypass L1 allocation (stream data never re-hits L1) while
// keeping L2 residency (R11's nt lost L2 -> 734MB HBM fetch; sc0 keeps ~38MB).
template <int USE_GX>
__global__ __launch_bounds__(1024, 1) void rel_lstm(
    const float* __restrict__ x,
    const float* __restrict__ bf_g, const float* __restrict__ bi_g,
    const float* __restrict__ bo_g, const float* __restrict__ bg_g,
    const float* __restrict__ vv_g,
    unsigned char* __restrict__ ws, float* __restrict__ out) {
    const int tid = threadIdx.x;
    const int b   = blockIdx.x;
    const int wv  = tid >> 6;
    const int ln  = tid & 63;
    const int h16 = (wv << 4) | (ln & 15);   // owner h
    const int kc  = ln >> 4;                 // in-wave k-chunk 0..3

    const uint4* __restrict__ WP   = (const uint4*)(ws + WP_OFF);
    const uint4* __restrict__ VaP8 = (const uint4*)(ws + VAP8_OFF);  // UaP8 = VaP8 + 8192
    const uint2* __restrict__ GX   = (const uint2*)(ws + GX_OFF);
    DECL_RSRC(rWP, ws + WP_OFF);
    DECL_RSRC(rVU, ws + VAP8_OFF);
    DECL_RSRC(rGX, ws + GX_OFF);

    __shared__ __align__(16) _Float16 s_in_h[NH + NI];   // half st | half x (non-GX)
    __shared__ __align__(16) _Float16 s_hid_h[NH];       // half h_{t-1}
    __shared__ __align__(16) float s_q[NH];              // Va @ st (combined)
    __shared__ __align__(16) float s_v[NH];
    __shared__ __align__(16) float s_mem[LK][NH];        // hidden ring (float)
    __shared__ __align__(16) float s_memua[LK][NH + 8];  // Ua@h ring (+8 pad)
    __shared__ __align__(16) float s_lraw[RS * NH];      // long-mem raw hiddens
    __shared__ __align__(16) float s_lua[RS * NH];       // long-mem Ua@h
    __shared__ float s_es[NS], s_al[NS];
    __shared__ float s_scores[T_STEPS];
    __shared__ float s_mask[RS], s_buck[RS];
    __shared__ float s_minv;
    __shared__ int s_minp, s_fill, s_upd, s_pos;

    // ---- init ----
    for (int i = tid; i < LK * NH; i += 1024) ((float*)s_mem)[i] = 0.f;
    for (int i = tid; i < LK * (NH + 8); i += 1024) ((float*)s_memua)[i] = 0.f;
    for (int i = tid; i < RS * NH; i += 1024) { s_lraw[i] = 0.f; s_lua[i] = 0.f; }
    if (tid < T_STEPS) s_scores[tid] = 0.f;
    if (tid < NH) s_v[tid] = vv_g[tid];
    if (tid < (NH + NI) / 2) ((unsigned int*)s_in_h)[tid] = 0u;
    if (tid < RS) { s_mask[tid] = -1e30f; s_buck[tid] = 0.f; }
    if (tid == 0) { s_fill = 0; s_upd = 0; s_pos = 0; s_minv = 0.f; s_minp = 0; }
    float bfv = 0.f, biv = 0.f, bov = 0.f, bgv = 0.f;
    if (kc == 0) { bfv = bf_g[h16]; biv = bi_g[h16]; bov = bo_g[h16]; bgv = bg_g[h16]; }
    if (!USE_GX && tid < 64) {            // x_0 half-pack
        float2 xv = ((const float2*)(x + (size_t)b * NI))[tid];
        __half2 hx = __floats2half2_rn(xv.x, xv.y);
        ((unsigned int*)s_in_h)[NH / 2 + tid] = *(unsigned int*)&hx;
    }
    float ct = 0.f;
    int base = 0;
    __syncthreads();

    for (int t = 0; t < T_STEPS; ++t) {
        float evA = 0.f, evB = 0.f;
        uint2 gx = {0u, 0u};
        if (USE_GX && kc == 0) gx = LD8(rGX, GX, ((size_t)t * NB + b) * NH + h16);
        if (t > 0) {
            // ---- P1: Va@st (waves 0-7) / Ua@h_{t-1} (waves 8-15), sc0 loads, fdot2 ----
            {
                const int pofs = (wv < 8) ? 0 : 8192;          // UaP8 entry offset
                const uint4* SRC = (wv < 8) ? (const uint4*)s_in_h : (const uint4*)s_hid_h;
                const int hh = ((wv & 7) << 5) | (ln & 31);    // output h (32 per wave)
                const int ch = ln >> 5;                        // k half 0/1
                float acc = 0.f;
#pragma unroll 8
                for (int jj = 0; jj < 16; ++jj) {
                    int j = (ch << 4) | jj;
                    uint4 w = LD16(rVU, VaP8, (j << 8) + hh + pofs);
                    uint4 s = SRC[j];                          // LDS broadcast b128
                    acc = hdot(w.x, s.x, acc);
                    acc = hdot(w.y, s.y, acc);
                    acc = hdot(w.z, s.z, acc);
                    acc = hdot(w.w, s.w, acc);
                }
                acc += __shfl_xor(acc, 32, 64);
                if (ch == 0) {
                    if (wv < 8) s_q[hh] = acc;
                    else        s_memua[(base + LK - 1) & (LK - 1)][hh] = acc; // persist newest
                }
                if (kc == 1) {               // prefetch evictee (slot stable since t-15)
                    int p0 = base & (LK - 1);
                    evA = s_mem[p0][h16];
                    evB = s_memua[p0][h16];
                }
                if (!USE_GX && tid < 64) {                     // x_t half-pack
                    float2 xv = ((const float2*)(x + ((size_t)t * NB + b) * NI))[tid];
                    __half2 hx = __floats2half2_rn(xv.x, xv.y);
                    ((unsigned int*)s_in_h)[NH / 2 + tid] = *(unsigned int*)&hx;
                }
            }
            __syncthreads();
            // ---- P2: attention scores (48 rows x 16 lanes, float4 loads) + argmin ----
            if (tid < 768) {
                const int row = tid >> 4, l = tid & 15;
                bool skip;
                const float* ua;
                if (row < LK) { skip = row < LK - t; ua = s_memua[(base + row) & (LK - 1)]; }
                else          { skip = s_mask[row - LK] < -1e29f; ua = s_lua + (row - LK) * NH; }
                float esv = -1e30f;
                if (!skip) {
                    float p = 0.f;
#pragma unroll
                    for (int jj = 0; jj < 4; ++jj) {
                        int hh = (l << 2) + (jj << 6);   // 2-way bank aliasing only
                        float4 q4 = *(const float4*)(s_q + hh);
                        float4 v4 = *(const float4*)(s_v + hh);
                        float4 u4 = *(const float4*)(ua + hh);
                        p += v4.x * ftanh(q4.x + u4.x);
                        p += v4.y * ftanh(q4.y + u4.y);
                        p += v4.z * ftanh(q4.z + u4.z);
                        p += v4.w * ftanh(q4.w + u4.w);
                    }
                    p += __shfl_xor(p, 1, 16);
                    p += __shfl_xor(p, 2, 16);
                    p += __shfl_xor(p, 4, 16);
                    p += __shfl_xor(p, 8, 16);
                    esv = p;
                }
                if (l == 0) s_es[row] = esv;
            } else if (tid >= 960 && tid < 992) {   // first-min argmin over s_buck
                int l = tid - 960;
                float v = s_buck[l]; int idx = l;
#pragma unroll
                for (int off = 1; off < 32; off <<= 1) {
                    float v2 = __shfl_xor(v, off, 32);
                    int  i2 = __shfl_xor(idx, off, 32);
                    if (v2 < v || (v2 == v && i2 < idx)) { v = v2; idx = i2; }
                }
                if (l == 0) { s_minv = v; s_minp = idx; }
            }
            __syncthreads();
            // ---- P3: softmax + detached score accum + bucket decision (wave 0) ----
            if (tid < 64) {
                float e = (tid < NS) ? s_es[tid] : -1e30f;
                float m = e;
#pragma unroll
                for (int off = 32; off; off >>= 1) m = fmaxf(m, __shfl_xor(m, off, 64));
                float a = (tid < NS) ? __expf(e - m) : 0.f;
                float ssum = a;
#pragma unroll
                for (int off = 32; off; off >>= 1) ssum += __shfl_xor(ssum, off, 64);
                float al = a * __builtin_amdgcn_rcpf(ssum);
                if (tid < NS) s_al[tid] = al;
                float cs = 0.f;
                if (tid < LK) {
                    int time = t - LK + tid;
                    if (time >= 0) {
                        float ns = s_scores[time] + al;
                        s_scores[time] = ns;
                        cs = ns;                      // lane 0: candidate score, in-register
                    }
                }
                if (tid == 0) {
                    int upd = 0, pos = 0;
                    if (t >= LK) {
                        int fill = s_fill;
                        bool full = fill >= RS;
                        upd = (!full) || (cs > s_minv);
                        pos = full ? s_minp : fill;
                        if (upd) { s_mask[pos] = 0.f; s_buck[pos] = cs; if (!full) s_fill = fill + 1; }
                    }
                    s_upd = upd; s_pos = pos;
                }
            }
            __syncthreads();
            // ---- P4: ct_att (12 slots per kc, in-wave combine) + st ----
            {
                float catt = 0.f;
                const int n0 = kc * 12;
#pragma unroll
                for (int n = n0; n < n0 + 12; ++n) {
                    float a = s_al[n];
                    if (n < LK) catt += a * s_mem[(base + n) & (LK - 1)][h16];
                    else if (a != 0.f) catt += a * s_lraw[(n - LK) * NH + h16];
                }
                catt += __shfl_xor(catt, 16, 64);
                catt += __shfl_xor(catt, 32, 64);
                if (kc == 0) {
                    float stv = 0.5f * (s_mem[(base + LK - 1) & (LK - 1)][h16] + catt);
                    s_in_h[h16] = (_Float16)stv;     // half shadow (only consumer is fdot2)
                }
            }
            __syncthreads();
        }
        // ---- P5: gates via fdot2 (in-wave 4-way k-split), sc0 weight loads ----
        {
            constexpr int KP = USE_GX ? 32 : 48;
            const unsigned int* S2 = (const unsigned int*)s_in_h;
            float af = 0.f, ai = 0.f, ao = 0.f, ag = 0.f;
            const int lo = kc * KP;
#pragma unroll 8
            for (int k2 = lo; k2 < lo + KP; ++k2) {
                uint4 w = LD16(rWP, WP, (k2 << 8) + h16);
                unsigned int s2 = S2[k2];            // LDS broadcast b32
                af = hdot(w.x, s2, af);
                ai = hdot(w.y, s2, ai);
                ao = hdot(w.z, s2, ao);
                ag = hdot(w.w, s2, ag);
            }
            af += __shfl_xor(af, 16, 64); af += __shfl_xor(af, 32, 64);
            ai += __shfl_xor(ai, 16, 64); ai += __shfl_xor(ai, 32, 64);
            ao += __shfl_xor(ao, 16, 64); ao += __shfl_xor(ao, 32, 64);
            ag += __shfl_xor(ag, 16, 64); ag += __shfl_xor(ag, 32, 64);
            if (kc == 0) {
                float pf = af + bfv, pi = ai + biv, po = ao + bov, pg = ag + bgv;
                if (USE_GX) {
                    float2 fi = __half22float2(*(const __half2*)&gx.x);
                    float2 og = __half22float2(*(const __half2*)&gx.y);
                    pf += fi.x; pi += fi.y; po += og.x; pg += og.y;
                }
                float f  = fsig(pf);
                float ii = fsig(pi);
                float o  = fsig(po);
                float g  = ftanh(pg);
                ct = f * ct + ii * g;                // t=0: ct=0 -> matches reference
                float hid = o * ftanh(ct);
                out[((size_t)t * NB + b) * NH + h16] = hid;
                s_mem[base & (LK - 1)][h16] = hid;
                s_hid_h[h16] = (_Float16)hid;
            } else if (kc == 1 && s_upd) {           // eviction writes (after P4 lraw reads)
                s_lraw[s_pos * NH + h16] = evA;
                s_lua[s_pos * NH + h16]  = evB;
            }
        }
        base++;
        __syncthreads();
    }
}

extern "C" void kernel_launch(void* const* d_in, const int* in_sizes, int n_in,
                              void* d_out, int out_size, void* d_ws, size_t ws_size,
                              hipStream_t stream) {
    const float* x  = (const float*)d_in[0];
    const float* Wf = (const float*)d_in[1];
    const float* bf = (const float*)d_in[2];
    const float* Wi = (const float*)d_in[3];
    const float* bi = (const float*)d_in[4];
    const float* Wo = (const float*)d_in[5];
    const float* bo = (const float*)d_in[6];
    const float* Wg = (const float*)d_in[7];
    const float* bg = (const float*)d_in[8];
    const float* Ua = (const float*)d_in[9];
    const float* Va = (const float*)d_in[10];
    const float* vv = (const float*)d_in[11];
    unsigned char* ws = (unsigned char*)d_ws;
    float* out = (float*)d_out;

    prep_weights<<<256, 256, 0, stream>>>(Wf, Wi, Wo, Wg, Ua, Va, ws);
    if (ws_size >= WS_NEED) {
        gx_gemm<<<dim3(T_STEPS, 4), 256, 0, stream>>>(x, ws);
        rel_lstm<1><<<NB, 1024, 0, stream>>>(x, bf, bi, bo, bg, vv, ws, out);
    } else {
        rel_lstm<0><<<NB, 1024, 0, stream>>>(x, bf, bi, bo, bg, vv, ws, out);
    }
}